// Round 2
// baseline (423.840 us; speedup 1.0000x reference)
//
#include <hip/hip_runtime.h>

// Problem constants
#define NB    128
#define NWAY  2
#define NSHOT 6
#define DD    256
#define NQ    32

// Workspace layout (float offsets)
//  tb_shot : [1536][2][256]  (T | Bv+b1 per shot embedding)
//  tb_query: [4096][2][256]
//  sum_ss  : [256][256]      ([b*2+w][n])
#define TB_SHOT_OFF   0
#define TB_QUERY_OFF  786432
#define SUM_SS_OFF    2883584
#define WS_FLOATS     2949120

// ---------------------------------------------------------------------------
// Kernel A: per-embedding first-layer transform.
//   T[e]  = e @ W1[0:256, :]
//   Bv[e] = e @ W1[256:512, :] + b1     (bias folded here)
// Blocks 0..95  -> shot embeddings (16/block, 1536 total)
// Blocks 96..351-> query embeddings (16/block, 4096 total)
// ---------------------------------------------------------------------------
__global__ __launch_bounds__(256) void k_embed(
    const float* __restrict__ x_shot, const float* __restrict__ x_query,
    const float* __restrict__ W1, const float* __restrict__ b1,
    float* __restrict__ tb_shot, float* __restrict__ tb_query)
{
    __shared__ __align__(16) float lds[16][DD];
    const int blk = blockIdx.x;
    const int t = threadIdx.x;
    const float* src;
    float* dst;
    int row0;
    if (blk < 96) { src = x_shot;  dst = tb_shot;  row0 = blk * 16; }
    else          { src = x_query; dst = tb_query; row0 = (blk - 96) * 16; }

    // stage 16 rows (4096 floats) into LDS, float4-coalesced
    const float4* s4 = (const float4*)(src + (size_t)row0 * DD);
    float4* l4 = (float4*)&lds[0][0];
#pragma unroll
    for (int i = 0; i < 4; ++i) l4[t + 256 * i] = s4[t + 256 * i];
    __syncthreads();

    float acc_t[16], acc_b[16];
#pragma unroll
    for (int r = 0; r < 16; ++r) { acc_t[r] = 0.f; acc_b[r] = 0.f; }

    const float* wt = W1 + t;              // column t of W1_top
    const float* wb = W1 + 256 * 256 + t;  // column t of W1_bot
    for (int k4 = 0; k4 < 64; ++k4) {
        const int kb = k4 * 4;
        const float wt0 = wt[(kb+0)*256], wt1 = wt[(kb+1)*256],
                    wt2 = wt[(kb+2)*256], wt3 = wt[(kb+3)*256];
        const float wb0 = wb[(kb+0)*256], wb1 = wb[(kb+1)*256],
                    wb2 = wb[(kb+2)*256], wb3 = wb[(kb+3)*256];
#pragma unroll
        for (int r = 0; r < 16; ++r) {
            const float4 av = *(const float4*)&lds[r][kb];   // wave-uniform broadcast
            acc_t[r] += av.x*wt0 + av.y*wt1 + av.z*wt2 + av.w*wt3;
            acc_b[r] += av.x*wb0 + av.y*wb1 + av.z*wb2 + av.w*wb3;
        }
    }
    const float b1v = b1[t];
#pragma unroll
    for (int r = 0; r < 16; ++r) {
        dst[(size_t)(row0 + r) * 512 + t]       = acc_t[r];
        dst[(size_t)(row0 + r) * 512 + 256 + t] = acc_b[r] + b1v;
    }
}

// ---------------------------------------------------------------------------
// Kernel B: shot-shot relation sums. One block per (b,w) = 256 blocks.
//   sum_ss[b,w] = sum over 30 ordered shot pairs (i!=j) of
//                 ReLU( ReLU(T[j] + Bv[i]) @ W2 + b2 )
// Shot T/Bv slices live in registers (12 floats/thread) — no LDS staging.
// ---------------------------------------------------------------------------
__global__ __launch_bounds__(256) void k_shotpairs(
    const float* __restrict__ tb_shot,
    const float* __restrict__ W2, const float* __restrict__ b2,
    float* __restrict__ sum_ss)
{
    __shared__ __align__(16) float a[30][DD];    // 30 KB
    __shared__ __align__(16) float red[2][DD];   //  2 KB
    const int bw = blockIdx.x;
    const int t = threadIdx.x;

    // thread t owns column t of every activation row
    const float* g = tb_shot + (size_t)bw * 6 * 512;
    float Tv[6], Bv[6];
#pragma unroll
    for (int s = 0; s < 6; ++s) {
        Tv[s] = g[s * 512 + t];
        Bv[s] = g[s * 512 + 256 + t];   // b1 already folded
    }
    {
        int p = 0;
#pragma unroll
        for (int i = 0; i < 6; ++i) {
#pragma unroll
            for (int j = 0; j < 6; ++j) {
                if (i == j) continue;
                const float v = Tv[j] + Bv[i];
                a[p][t] = v > 0.f ? v : 0.f;
                ++p;
            }
        }
    }
    __syncthreads();

    // GEMM [30x256] @ W2, register tile: 15 rows x 2 cols per thread
    const int half = t >> 7;           // 0 -> pairs 0..14, 1 -> pairs 15..29
    const int n0 = (t & 127) * 2;
    float acc[15][2];
#pragma unroll
    for (int i = 0; i < 15; ++i) { acc[i][0] = 0.f; acc[i][1] = 0.f; }

    for (int k4 = 0; k4 < 64; ++k4) {
        const int kb = k4 * 4;
        const float2 w0 = *(const float2*)&W2[(kb+0)*256 + n0];
        const float2 w1 = *(const float2*)&W2[(kb+1)*256 + n0];
        const float2 w2 = *(const float2*)&W2[(kb+2)*256 + n0];
        const float2 w3 = *(const float2*)&W2[(kb+3)*256 + n0];
#pragma unroll
        for (int q = 0; q < 15; ++q) {
            const float4 av = *(const float4*)&a[half*15 + q][kb];  // broadcast
            acc[q][0] += av.x*w0.x + av.y*w1.x + av.z*w2.x + av.w*w3.x;
            acc[q][1] += av.x*w0.y + av.y*w1.y + av.z*w2.y + av.w*w3.y;
        }
    }
    const float2 b2v = *(const float2*)&b2[n0];
    float s0 = 0.f, s1 = 0.f;
#pragma unroll
    for (int q = 0; q < 15; ++q) {
        const float h0 = acc[q][0] + b2v.x; s0 += h0 > 0.f ? h0 : 0.f;
        const float h1 = acc[q][1] + b2v.y; s1 += h1 > 0.f ? h1 : 0.f;
    }
    red[half][n0] = s0; red[half][n0 + 1] = s1;
    __syncthreads();
    sum_ss[(size_t)bw * DD + t] = red[0][t] + red[1][t];
}

// ---------------------------------------------------------------------------
// Kernel C: query pairs + rel-sum + f-MLP. One block per (b,q) = 4096 blocks,
// both ways handled by thread halves. LDS 27 KB -> 5 blocks/CU.
// ---------------------------------------------------------------------------
__global__ __launch_bounds__(256) void k_query(
    const float* __restrict__ tb_shot, const float* __restrict__ tb_query,
    const float* __restrict__ sum_ss,
    const float* __restrict__ W2, const float* __restrict__ b2,
    const float* __restrict__ F1, const float* __restrict__ fb1,
    const float* __restrict__ F2, const float* __restrict__ fb2,
    float* __restrict__ out)
{
    __shared__ __align__(16) float a[24][DD];     // 24 KB (12 rows per way)
    __shared__ __align__(16) float rel[2][DD];    //  2 KB
    __shared__ __align__(16) float red[256];      //  1 KB

    const int bq = blockIdx.x;           // b*32+q
    const int b  = bq >> 5;
    const int t  = threadIdx.x;

    // 24 layer-1 rows: per way w, rows (i=query, j=shot s) and (i=shot s, j=query).
    // Query/shot T|Bv slices read straight from L2 (coalesced, heavily reused).
    const float qT = tb_query[(size_t)bq * 512 + t];
    const float qB = tb_query[(size_t)bq * 512 + 256 + t];
    const float* gs = tb_shot + (size_t)b * 12 * 512;
#pragma unroll
    for (int w = 0; w < 2; ++w) {
#pragma unroll
        for (int s = 0; s < 6; ++s) {
            const float sT = gs[(w*6 + s) * 512 + t];
            const float sB = gs[(w*6 + s) * 512 + 256 + t];
            const float v0 = sT + qB;            // i=query, j=shot
            a[w*12 + s][t] = v0 > 0.f ? v0 : 0.f;
            const float v1 = qT + sB;            // i=shot, j=query
            a[w*12 + 6 + s][t] = v1 > 0.f ? v1 : 0.f;
        }
    }
    __syncthreads();

    // GEMM [12x256] @ W2 per way; thread tile 12 rows x 2 cols
    const int w  = t >> 7;               // way
    const int n0 = (t & 127) * 2;
    float acc[12][2];
#pragma unroll
    for (int i = 0; i < 12; ++i) { acc[i][0] = 0.f; acc[i][1] = 0.f; }

    for (int k4 = 0; k4 < 64; ++k4) {
        const int kb = k4 * 4;
        const float2 w0 = *(const float2*)&W2[(kb+0)*256 + n0];
        const float2 w1 = *(const float2*)&W2[(kb+1)*256 + n0];
        const float2 w2 = *(const float2*)&W2[(kb+2)*256 + n0];
        const float2 w3 = *(const float2*)&W2[(kb+3)*256 + n0];
#pragma unroll
        for (int p = 0; p < 12; ++p) {
            const float4 av = *(const float4*)&a[w*12 + p][kb];     // broadcast
            acc[p][0] += av.x*w0.x + av.y*w1.x + av.z*w2.x + av.w*w3.x;
            acc[p][1] += av.x*w0.y + av.y*w1.y + av.z*w2.y + av.w*w3.y;
        }
    }
    const float2 b2v = *(const float2*)&b2[n0];
    const float2 ss  = *(const float2*)&sum_ss[(size_t)b * 512 + w * 256 + n0];
    float r0 = ss.x, r1 = ss.y;
#pragma unroll
    for (int p = 0; p < 12; ++p) {
        const float h0 = acc[p][0] + b2v.x; r0 += h0 > 0.f ? h0 : 0.f;
        const float h1 = acc[p][1] + b2v.y; r1 += h1 > 0.f ? h1 : 0.f;
    }
    rel[w][n0] = r0; rel[w][n0 + 1] = r1;
    __syncthreads();

    // f-MLP: f = ReLU(rel @ F1 + fb1); logit = f @ F2 + fb2
    float f0 = 0.f, f1 = 0.f;
    for (int k4 = 0; k4 < 64; ++k4) {
        const int kb = k4 * 4;
        const float4 rv = *(const float4*)&rel[w][kb];              // broadcast
        const float2 g0 = *(const float2*)&F1[(kb+0)*256 + n0];
        const float2 g1 = *(const float2*)&F1[(kb+1)*256 + n0];
        const float2 g2 = *(const float2*)&F1[(kb+2)*256 + n0];
        const float2 g3 = *(const float2*)&F1[(kb+3)*256 + n0];
        f0 += rv.x*g0.x + rv.y*g1.x + rv.z*g2.x + rv.w*g3.x;
        f1 += rv.x*g0.y + rv.y*g1.y + rv.z*g2.y + rv.w*g3.y;
    }
    f0 += fb1[n0];     f0 = f0 > 0.f ? f0 : 0.f;
    f1 += fb1[n0 + 1]; f1 = f1 > 0.f ? f1 : 0.f;
    red[t] = f0 * F2[n0] + f1 * F2[n0 + 1];
    __syncthreads();
#pragma unroll
    for (int off = 64; off >= 1; off >>= 1) {
        if ((t & 127) < off) red[t] += red[t + off];
        __syncthreads();
    }
    if (t == 0)   out[(size_t)bq * 2 + 0] = red[0]   + fb2[0];
    if (t == 128) out[(size_t)bq * 2 + 1] = red[128] + fb2[0];
}

// ---------------------------------------------------------------------------
extern "C" void kernel_launch(void* const* d_in, const int* in_sizes, int n_in,
                              void* d_out, int out_size, void* d_ws, size_t ws_size,
                              hipStream_t stream)
{
    const float* x_shot  = (const float*)d_in[0];
    const float* x_query = (const float*)d_in[1];
    const float* W1  = (const float*)d_in[2];
    const float* b1  = (const float*)d_in[3];
    const float* W2  = (const float*)d_in[4];
    const float* b2  = (const float*)d_in[5];
    const float* F1  = (const float*)d_in[6];
    const float* fb1 = (const float*)d_in[7];
    const float* F2  = (const float*)d_in[8];
    const float* fb2 = (const float*)d_in[9];
    float* out = (float*)d_out;
    float* ws  = (float*)d_ws;

    float* tb_shot  = ws + TB_SHOT_OFF;
    float* tb_query = ws + TB_QUERY_OFF;
    float* sum_ss   = ws + SUM_SS_OFF;

    hipLaunchKernelGGL(k_embed, dim3(352), dim3(256), 0, stream,
                       x_shot, x_query, W1, b1, tb_shot, tb_query);
    hipLaunchKernelGGL(k_shotpairs, dim3(256), dim3(256), 0, stream,
                       tb_shot, W2, b2, sum_ss);
    hipLaunchKernelGGL(k_query, dim3(4096), dim3(256), 0, stream,
                       tb_shot, tb_query, sum_ss, W2, b2, F1, fb1, F2, fb2, out);
}

// Round 3
// 392.072 us; speedup vs baseline: 1.0810x; 1.0810x over previous
//
#include <hip/hip_runtime.h>

typedef _Float16 half8 __attribute__((ext_vector_type(8)));
typedef _Float16 half4 __attribute__((ext_vector_type(4)));
typedef float f32x4 __attribute__((ext_vector_type(4)));

// Problem constants
#define NB    128
#define NWAY  2
#define NSHOT 6
#define DD    256
#define NQ    32

// Workspace layout (float offsets)
//  tb_shot : [1536][2][256]  (T | Bv+b1 per shot embedding)
//  tb_query: [4096][2][256]
//  sum_ss  : [256][256]      ([b*2+w][n])
//  then fp16 regions: w2t_hi [256n][256k], w2t_lo [256n][256k]
#define TB_SHOT_OFF   0
#define TB_QUERY_OFF  786432
#define SUM_SS_OFF    2883584
#define W2T_OFF       2949120   // float offset where fp16 data begins

// ---------------------------------------------------------------------------
// Kernel P: split W2 (fp32 [k][n]) into transposed fp16 hi/lo: w2t[n][k].
// hi = fp16(v), lo = fp16(v - hi). 256 blocks handle 16x16 tiles.
// ---------------------------------------------------------------------------
__global__ __launch_bounds__(256) void k_prep(
    const float* __restrict__ W2,
    _Float16* __restrict__ w2t_hi, _Float16* __restrict__ w2t_lo)
{
    __shared__ float lds[16][17];
    const int bid = blockIdx.x;
    const int kt = bid & 15, nt = bid >> 4;
    const int tx = threadIdx.x & 15, ty = threadIdx.x >> 4;
    lds[ty][tx] = W2[(size_t)(kt * 16 + ty) * 256 + nt * 16 + tx];
    __syncthreads();
    const float v = lds[tx][ty];          // = W2[kt*16+tx][nt*16+ty]
    const _Float16 h  = (_Float16)v;
    const _Float16 lo = (_Float16)(v - (float)h);
    const size_t o = (size_t)(nt * 16 + ty) * 256 + (size_t)(kt * 16 + tx);
    w2t_hi[o] = h;
    w2t_lo[o] = lo;
}

// ---------------------------------------------------------------------------
// Kernel A: per-embedding first-layer transform. (unchanged, verified exact)
//   T[e]  = e @ W1[0:256, :]
//   Bv[e] = e @ W1[256:512, :] + b1
// ---------------------------------------------------------------------------
__global__ __launch_bounds__(256) void k_embed(
    const float* __restrict__ x_shot, const float* __restrict__ x_query,
    const float* __restrict__ W1, const float* __restrict__ b1,
    float* __restrict__ tb_shot, float* __restrict__ tb_query)
{
    __shared__ __align__(16) float lds[16][DD];
    const int blk = blockIdx.x;
    const int t = threadIdx.x;
    const float* src;
    float* dst;
    int row0;
    if (blk < 96) { src = x_shot;  dst = tb_shot;  row0 = blk * 16; }
    else          { src = x_query; dst = tb_query; row0 = (blk - 96) * 16; }

    const float4* s4 = (const float4*)(src + (size_t)row0 * DD);
    float4* l4 = (float4*)&lds[0][0];
#pragma unroll
    for (int i = 0; i < 4; ++i) l4[t + 256 * i] = s4[t + 256 * i];
    __syncthreads();

    float acc_t[16], acc_b[16];
#pragma unroll
    for (int r = 0; r < 16; ++r) { acc_t[r] = 0.f; acc_b[r] = 0.f; }

    const float* wt = W1 + t;
    const float* wb = W1 + 256 * 256 + t;
    for (int k4 = 0; k4 < 64; ++k4) {
        const int kb = k4 * 4;
        const float wt0 = wt[(kb+0)*256], wt1 = wt[(kb+1)*256],
                    wt2 = wt[(kb+2)*256], wt3 = wt[(kb+3)*256];
        const float wb0 = wb[(kb+0)*256], wb1 = wb[(kb+1)*256],
                    wb2 = wb[(kb+2)*256], wb3 = wb[(kb+3)*256];
#pragma unroll
        for (int r = 0; r < 16; ++r) {
            const float4 av = *(const float4*)&lds[r][kb];
            acc_t[r] += av.x*wt0 + av.y*wt1 + av.z*wt2 + av.w*wt3;
            acc_b[r] += av.x*wb0 + av.y*wb1 + av.z*wb2 + av.w*wb3;
        }
    }
    const float b1v = b1[t];
#pragma unroll
    for (int r = 0; r < 16; ++r) {
        dst[(size_t)(row0 + r) * 512 + t]       = acc_t[r];
        dst[(size_t)(row0 + r) * 512 + 256 + t] = acc_b[r] + b1v;
    }
}

// ---------------------------------------------------------------------------
// Kernel B: shot-shot relation sums. (unchanged, verified exact)
// ---------------------------------------------------------------------------
__global__ __launch_bounds__(256) void k_shotpairs(
    const float* __restrict__ tb_shot,
    const float* __restrict__ W2, const float* __restrict__ b2,
    float* __restrict__ sum_ss)
{
    __shared__ __align__(16) float a[30][DD];
    __shared__ __align__(16) float red[2][DD];
    const int bw = blockIdx.x;
    const int t = threadIdx.x;

    const float* g = tb_shot + (size_t)bw * 6 * 512;
    float Tv[6], Bv[6];
#pragma unroll
    for (int s = 0; s < 6; ++s) {
        Tv[s] = g[s * 512 + t];
        Bv[s] = g[s * 512 + 256 + t];
    }
    {
        int p = 0;
#pragma unroll
        for (int i = 0; i < 6; ++i) {
#pragma unroll
            for (int j = 0; j < 6; ++j) {
                if (i == j) continue;
                const float v = Tv[j] + Bv[i];
                a[p][t] = v > 0.f ? v : 0.f;
                ++p;
            }
        }
    }
    __syncthreads();

    const int half = t >> 7;
    const int n0 = (t & 127) * 2;
    float acc[15][2];
#pragma unroll
    for (int i = 0; i < 15; ++i) { acc[i][0] = 0.f; acc[i][1] = 0.f; }

    for (int k4 = 0; k4 < 64; ++k4) {
        const int kb = k4 * 4;
        const float2 w0 = *(const float2*)&W2[(kb+0)*256 + n0];
        const float2 w1 = *(const float2*)&W2[(kb+1)*256 + n0];
        const float2 w2 = *(const float2*)&W2[(kb+2)*256 + n0];
        const float2 w3 = *(const float2*)&W2[(kb+3)*256 + n0];
#pragma unroll
        for (int q = 0; q < 15; ++q) {
            const float4 av = *(const float4*)&a[half*15 + q][kb];
            acc[q][0] += av.x*w0.x + av.y*w1.x + av.z*w2.x + av.w*w3.x;
            acc[q][1] += av.x*w0.y + av.y*w1.y + av.z*w2.y + av.w*w3.y;
        }
    }
    const float2 b2v = *(const float2*)&b2[n0];
    float s0 = 0.f, s1 = 0.f;
#pragma unroll
    for (int q = 0; q < 15; ++q) {
        const float h0 = acc[q][0] + b2v.x; s0 += h0 > 0.f ? h0 : 0.f;
        const float h1 = acc[q][1] + b2v.y; s1 += h1 > 0.f ? h1 : 0.f;
    }
    red[half][n0] = s0; red[half][n0 + 1] = s1;
    __syncthreads();
    sum_ss[(size_t)bw * DD + t] = red[0][t] + red[1][t];
}

// ---------------------------------------------------------------------------
// Kernel C: query pairs via split-fp16 MFMA + rel-sum + f-MLP.
// One block per (b,q) = 4096 blocks, 4 waves.
//
// A-tile in LDS: rows 0..11 = way0's 12 pair-rows, 12..15 zero pad,
//                16..27 = way1, 28..31 pad. fp16 hi + lo, XOR-swizzled
//                (byte ^= (row&7)<<4) so ds_read_b128 of MFMA A-fragments
//                (16 rows @ 512 B stride) is conflict-free.
// GEMM: D = A[16x32] x W2T[32x16] accumulated over 8 K-steps; split products
//       hi*hi + lo*hi + hi*lo (error ~2^-22, fp32-class).
// Wave wv handles n-tiles wv*4..wv*4+3 for BOTH ways (B fragments reused).
// ---------------------------------------------------------------------------
__global__ __launch_bounds__(256) void k_query(
    const float* __restrict__ tb_shot, const float* __restrict__ tb_query,
    const float* __restrict__ sum_ss,
    const _Float16* __restrict__ w2t_hi, const _Float16* __restrict__ w2t_lo,
    const float* __restrict__ b2,
    const float* __restrict__ F1, const float* __restrict__ fb1,
    const float* __restrict__ F2, const float* __restrict__ fb2,
    float* __restrict__ out)
{
    __shared__ __align__(16) _Float16 aHi[32 * 256];   // 16 KB
    __shared__ __align__(16) _Float16 aLo[32 * 256];   // 16 KB
    __shared__ __align__(16) float rel[2][DD];         //  2 KB
    __shared__ __align__(16) float red[256];           //  1 KB

    const int bq = blockIdx.x;           // b*32+q
    const int b  = bq >> 5;
    const int t  = threadIdx.x;
    const int tg = t >> 6;               // wave id / build row-group
    const int lane = t & 63;

    // ---- build phase: 24 layer-1 rows -> fp16 hi/lo in LDS (swizzled) ----
    // tg -> 6 rows, lane -> 4 consecutive cols.
    {
        const int c4 = lane * 4;                 // column (element) base
        const int w  = tg >> 1;                  // way
        const int side = tg & 1;                 // 0: sT+qB rows, 1: qT+sB rows
        const float4 qv = *(const float4*)&tb_query[(size_t)bq * 512 + (side ? 0 : 256) + c4];
        const float* gs = tb_shot + (size_t)b * 12 * 512 + (size_t)w * 6 * 512;
#pragma unroll
        for (int s = 0; s < 6; ++s) {
            const float4 sv = *(const float4*)&gs[s * 512 + (side ? 256 : 0) + c4];
            float v0 = sv.x + qv.x, v1 = sv.y + qv.y, v2 = sv.z + qv.z, v3 = sv.w + qv.w;
            v0 = v0 > 0.f ? v0 : 0.f;
            v1 = v1 > 0.f ? v1 : 0.f;
            v2 = v2 > 0.f ? v2 : 0.f;
            v3 = v3 > 0.f ? v3 : 0.f;
            half4 h, l;
            h.x = (_Float16)v0; l.x = (_Float16)(v0 - (float)h.x);
            h.y = (_Float16)v1; l.y = (_Float16)(v1 - (float)h.y);
            h.z = (_Float16)v2; l.z = (_Float16)(v2 - (float)h.z);
            h.w = (_Float16)v3; l.w = (_Float16)(v3 - (float)h.w);
            const int ar = w * 16 + side * 6 + s;                 // A row
            const int off = ar * 512 + ((lane * 8) ^ ((ar & 7) << 4));
            *(half4*)((char*)aHi + off) = h;
            *(half4*)((char*)aLo + off) = l;
        }
        // zero the pad rows 12..15 and 28..31 (hi and lo)
        half4 z; z.x = (_Float16)0.f; z.y = (_Float16)0.f; z.z = (_Float16)0.f; z.w = (_Float16)0.f;
        const int pr0 = 12 + tg, pr1 = 28 + tg;
        const int o0 = pr0 * 512 + ((lane * 8) ^ ((pr0 & 7) << 4));
        const int o1 = pr1 * 512 + ((lane * 8) ^ ((pr1 & 7) << 4));
        *(half4*)((char*)aHi + o0) = z;  *(half4*)((char*)aLo + o0) = z;
        *(half4*)((char*)aHi + o1) = z;  *(half4*)((char*)aLo + o1) = z;
    }
    __syncthreads();

    // ---- MFMA phase ----
    const int wv = tg;
    const int r  = lane & 15;            // A row-in-tile / B col-in-tile / D col
    const int gq = lane >> 4;            // k-group
    const int swz = (r & 7) << 4;
    f32x4 acc[2][4];
#pragma unroll
    for (int i = 0; i < 2; ++i)
#pragma unroll
        for (int j = 0; j < 4; ++j)
#pragma unroll
            for (int e = 0; e < 4; ++e) acc[i][j][e] = 0.f;

    const int aoff0 = r * 512;           // way-0 row byte base
    const int aoff1 = (16 + r) * 512;    // way-1
#pragma unroll
    for (int ks = 0; ks < 8; ++ks) {
        const int kb = (ks * 64 + gq * 16) ^ swz;          // swizzled k-byte
        const half8 aH0 = *(const half8*)((const char*)aHi + aoff0 + kb);
        const half8 aL0 = *(const half8*)((const char*)aLo + aoff0 + kb);
        const half8 aH1 = *(const half8*)((const char*)aHi + aoff1 + kb);
        const half8 aL1 = *(const half8*)((const char*)aLo + aoff1 + kb);
        const int kh = ks * 32 + gq * 8;                   // k half-index
#pragma unroll
        for (int nt = 0; nt < 4; ++nt) {
            const int n = (wv * 4 + nt) * 16 + r;
            const half8 bH = *(const half8*)&w2t_hi[(size_t)n * 256 + kh];
            const half8 bL = *(const half8*)&w2t_lo[(size_t)n * 256 + kh];
            acc[0][nt] = __builtin_amdgcn_mfma_f32_16x16x32_f16(aH0, bH, acc[0][nt], 0, 0, 0);
            acc[0][nt] = __builtin_amdgcn_mfma_f32_16x16x32_f16(aL0, bH, acc[0][nt], 0, 0, 0);
            acc[0][nt] = __builtin_amdgcn_mfma_f32_16x16x32_f16(aH0, bL, acc[0][nt], 0, 0, 0);
            acc[1][nt] = __builtin_amdgcn_mfma_f32_16x16x32_f16(aH1, bH, acc[1][nt], 0, 0, 0);
            acc[1][nt] = __builtin_amdgcn_mfma_f32_16x16x32_f16(aL1, bH, acc[1][nt], 0, 0, 0);
            acc[1][nt] = __builtin_amdgcn_mfma_f32_16x16x32_f16(aH1, bL, acc[1][nt], 0, 0, 0);
        }
    }

    // ---- epilogue: rel[w][n] = ss + sum_rows ReLU(acc + b2) ----
    // D layout: col = lane&15, row = (lane>>4)*4 + j. Rows 12..15 (gq==3) are pad.
#pragma unroll
    for (int nt = 0; nt < 4; ++nt) {
        const int n = (wv * 4 + nt) * 16 + r;
        const float b2n = b2[n];
#pragma unroll
        for (int w = 0; w < 2; ++w) {
            float p = 0.f;
            if (gq != 3) {
#pragma unroll
                for (int j = 0; j < 4; ++j) {
                    const float h = acc[w][nt][j] + b2n;
                    p += h > 0.f ? h : 0.f;
                }
            }
            p += __shfl_xor(p, 16);
            p += __shfl_xor(p, 32);
            if (lane < 16) rel[w][n] = p + sum_ss[(size_t)b * 512 + w * 256 + n];
        }
    }
    __syncthreads();

    // ---- f-MLP: f = ReLU(rel @ F1 + fb1); logit = f @ F2 + fb2 ----
    {
        const int wf = t >> 7;
        const int n0 = (t & 127) * 2;
        float f0 = 0.f, f1 = 0.f;
        for (int k4 = 0; k4 < 64; ++k4) {
            const int kb = k4 * 4;
            const float4 rv = *(const float4*)&rel[wf][kb];
            const float2 g0 = *(const float2*)&F1[(kb+0)*256 + n0];
            const float2 g1 = *(const float2*)&F1[(kb+1)*256 + n0];
            const float2 g2 = *(const float2*)&F1[(kb+2)*256 + n0];
            const float2 g3 = *(const float2*)&F1[(kb+3)*256 + n0];
            f0 += rv.x*g0.x + rv.y*g1.x + rv.z*g2.x + rv.w*g3.x;
            f1 += rv.x*g0.y + rv.y*g1.y + rv.z*g2.y + rv.w*g3.y;
        }
        f0 += fb1[n0];     f0 = f0 > 0.f ? f0 : 0.f;
        f1 += fb1[n0 + 1]; f1 = f1 > 0.f ? f1 : 0.f;
        red[t] = f0 * F2[n0] + f1 * F2[n0 + 1];
    }
    __syncthreads();
#pragma unroll
    for (int off = 64; off >= 1; off >>= 1) {
        if ((t & 127) < off) red[t] += red[t + off];
        __syncthreads();
    }
    if (t == 0)   out[(size_t)bq * 2 + 0] = red[0]   + fb2[0];
    if (t == 128) out[(size_t)bq * 2 + 1] = red[128] + fb2[0];
}

// ---------------------------------------------------------------------------
extern "C" void kernel_launch(void* const* d_in, const int* in_sizes, int n_in,
                              void* d_out, int out_size, void* d_ws, size_t ws_size,
                              hipStream_t stream)
{
    const float* x_shot  = (const float*)d_in[0];
    const float* x_query = (const float*)d_in[1];
    const float* W1  = (const float*)d_in[2];
    const float* b1  = (const float*)d_in[3];
    const float* W2  = (const float*)d_in[4];
    const float* b2  = (const float*)d_in[5];
    const float* F1  = (const float*)d_in[6];
    const float* fb1 = (const float*)d_in[7];
    const float* F2  = (const float*)d_in[8];
    const float* fb2 = (const float*)d_in[9];
    float* out = (float*)d_out;
    float* ws  = (float*)d_ws;

    float* tb_shot  = ws + TB_SHOT_OFF;
    float* tb_query = ws + TB_QUERY_OFF;
    float* sum_ss   = ws + SUM_SS_OFF;
    _Float16* w2t_hi = (_Float16*)(ws + W2T_OFF);
    _Float16* w2t_lo = w2t_hi + 256 * 256;

    hipLaunchKernelGGL(k_prep, dim3(256), dim3(256), 0, stream, W2, w2t_hi, w2t_lo);
    hipLaunchKernelGGL(k_embed, dim3(352), dim3(256), 0, stream,
                       x_shot, x_query, W1, b1, tb_shot, tb_query);
    hipLaunchKernelGGL(k_shotpairs, dim3(256), dim3(256), 0, stream,
                       tb_shot, W2, b2, sum_ss);
    hipLaunchKernelGGL(k_query, dim3(4096), dim3(256), 0, stream,
                       tb_shot, tb_query, sum_ss, w2t_hi, w2t_lo, b2,
                       F1, fb1, F2, fb2, out);
}

// Round 7
// 323.312 us; speedup vs baseline: 1.3109x; 1.2127x over previous
//
#include <hip/hip_runtime.h>

typedef _Float16 half8 __attribute__((ext_vector_type(8)));
typedef _Float16 half4 __attribute__((ext_vector_type(4)));
typedef float f32x4 __attribute__((ext_vector_type(4)));

// Problem constants
#define NB    128
#define NWAY  2
#define NSHOT 6
#define DD    256
#define NQ    32

// Workspace layout (float offsets)
//  tb_shot : [1536][2][256]  (T | Bv+b1 per shot embedding)
//  tb_query: [4096][2][256]
//  sum_ss  : [256][256]      ([b*2+w][n])
//  w2p_hi/w2p_lo: packed fp16 MFMA B-fragments [128 tiles][64 lanes][8]
#define TB_SHOT_OFF   0
#define TB_QUERY_OFF  786432
#define SUM_SS_OFF    2883584
#define W2P_OFF       2949120

// ---------------------------------------------------------------------------
// Kernel P: split W2 (fp32 [k][n]) into hi/lo fp16 MFMA B-fragments, packed
// fragment-linear: tile = ks*16 + ntile; w2p[tile][lane][e] = W2[k][n] with
// n = ntile*16 + (lane&15), k = ks*32 + (lane>>4)*8 + e.
// A wave's B-load is then one contiguous 1 KB dwordx4 read (coalesced).
// Content-identical to the round-3 verified gather (only relocated).
// ---------------------------------------------------------------------------
__global__ __launch_bounds__(256) void k_prep(
    const float* __restrict__ W2,
    _Float16* __restrict__ w2p_hi, _Float16* __restrict__ w2p_lo)
{
    const int tid  = blockIdx.x * 256 + threadIdx.x;   // 32 blocks
    const int tile = tid >> 6;          // [0,128) = ks*16 + ntile
    const int lane = tid & 63;
    const int ks = tile >> 4, ntile = tile & 15;
    const int gq = lane >> 4, r = lane & 15;
    const int n  = ntile * 16 + r;
#pragma unroll
    for (int e = 0; e < 8; ++e) {
        const int k = ks * 32 + gq * 8 + e;
        const float v = W2[(size_t)k * 256 + n];
        const _Float16 h = (_Float16)v;
        w2p_hi[(size_t)tile * 512 + lane * 8 + e] = h;
        w2p_lo[(size_t)tile * 512 + lane * 8 + e] = (_Float16)(v - (float)h);
    }
}

// ---------------------------------------------------------------------------
// Kernel A: per-embedding first-layer transform. (unchanged, verified exact)
// ---------------------------------------------------------------------------
__global__ __launch_bounds__(256) void k_embed(
    const float* __restrict__ x_shot, const float* __restrict__ x_query,
    const float* __restrict__ W1, const float* __restrict__ b1,
    float* __restrict__ tb_shot, float* __restrict__ tb_query)
{
    __shared__ __align__(16) float lds[16][DD];
    const int blk = blockIdx.x;
    const int t = threadIdx.x;
    const float* src;
    float* dst;
    int row0;
    if (blk < 96) { src = x_shot;  dst = tb_shot;  row0 = blk * 16; }
    else          { src = x_query; dst = tb_query; row0 = (blk - 96) * 16; }

    const float4* s4 = (const float4*)(src + (size_t)row0 * DD);
    float4* l4 = (float4*)&lds[0][0];
#pragma unroll
    for (int i = 0; i < 4; ++i) l4[t + 256 * i] = s4[t + 256 * i];
    __syncthreads();

    float acc_t[16], acc_b[16];
#pragma unroll
    for (int r = 0; r < 16; ++r) { acc_t[r] = 0.f; acc_b[r] = 0.f; }

    const float* wt = W1 + t;
    const float* wb = W1 + 256 * 256 + t;
    for (int k4 = 0; k4 < 64; ++k4) {
        const int kb = k4 * 4;
        const float wt0 = wt[(kb+0)*256], wt1 = wt[(kb+1)*256],
                    wt2 = wt[(kb+2)*256], wt3 = wt[(kb+3)*256];
        const float wb0 = wb[(kb+0)*256], wb1 = wb[(kb+1)*256],
                    wb2 = wb[(kb+2)*256], wb3 = wb[(kb+3)*256];
#pragma unroll
        for (int r = 0; r < 16; ++r) {
            const float4 av = *(const float4*)&lds[r][kb];
            acc_t[r] += av.x*wt0 + av.y*wt1 + av.z*wt2 + av.w*wt3;
            acc_b[r] += av.x*wb0 + av.y*wb1 + av.z*wb2 + av.w*wb3;
        }
    }
    const float b1v = b1[t];
#pragma unroll
    for (int r = 0; r < 16; ++r) {
        dst[(size_t)(row0 + r) * 512 + t]       = acc_t[r];
        dst[(size_t)(row0 + r) * 512 + 256 + t] = acc_b[r] + b1v;
    }
}

// ---------------------------------------------------------------------------
// Kernel B: shot-shot relation sums. (unchanged, verified exact)
// ---------------------------------------------------------------------------
__global__ __launch_bounds__(256) void k_shotpairs(
    const float* __restrict__ tb_shot,
    const float* __restrict__ W2, const float* __restrict__ b2,
    float* __restrict__ sum_ss)
{
    __shared__ __align__(16) float a[30][DD];
    __shared__ __align__(16) float red[2][DD];
    const int bw = blockIdx.x;
    const int t = threadIdx.x;

    const float* g = tb_shot + (size_t)bw * 6 * 512;
    float Tv[6], Bv[6];
#pragma unroll
    for (int s = 0; s < 6; ++s) {
        Tv[s] = g[s * 512 + t];
        Bv[s] = g[s * 512 + 256 + t];
    }
    {
        int p = 0;
#pragma unroll
        for (int i = 0; i < 6; ++i) {
#pragma unroll
            for (int j = 0; j < 6; ++j) {
                if (i == j) continue;
                const float v = Tv[j] + Bv[i];
                a[p][t] = v > 0.f ? v : 0.f;
                ++p;
            }
        }
    }
    __syncthreads();

    const int half = t >> 7;
    const int n0 = (t & 127) * 2;
    float acc[15][2];
#pragma unroll
    for (int i = 0; i < 15; ++i) { acc[i][0] = 0.f; acc[i][1] = 0.f; }

    for (int k4 = 0; k4 < 64; ++k4) {
        const int kb = k4 * 4;
        const float2 w0 = *(const float2*)&W2[(kb+0)*256 + n0];
        const float2 w1 = *(const float2*)&W2[(kb+1)*256 + n0];
        const float2 w2 = *(const float2*)&W2[(kb+2)*256 + n0];
        const float2 w3 = *(const float2*)&W2[(kb+3)*256 + n0];
#pragma unroll
        for (int q = 0; q < 15; ++q) {
            const float4 av = *(const float4*)&a[half*15 + q][kb];
            acc[q][0] += av.x*w0.x + av.y*w1.x + av.z*w2.x + av.w*w3.x;
            acc[q][1] += av.x*w0.y + av.y*w1.y + av.z*w2.y + av.w*w3.y;
        }
    }
    const float2 b2v = *(const float2*)&b2[n0];
    float s0 = 0.f, s1 = 0.f;
#pragma unroll
    for (int q = 0; q < 15; ++q) {
        const float h0 = acc[q][0] + b2v.x; s0 += h0 > 0.f ? h0 : 0.f;
        const float h1 = acc[q][1] + b2v.y; s1 += h1 > 0.f ? h1 : 0.f;
    }
    red[half][n0] = s0; red[half][n0 + 1] = s1;
    __syncthreads();
    sum_ss[(size_t)bw * DD + t] = red[0][t] + red[1][t];
}

// ---------------------------------------------------------------------------
// Kernel C: query pairs via split-fp16 MFMA + rel-sum + f-MLP.
// ROUND-3 VERIFIED STRUCTURE (1 query/block, 4096 blocks, 4 waves).
// Single change vs round 3: B fragments come from k_prep's packed w2p
// (one contiguous 1 KB wave-load per fragment) instead of the 512 B-stride
// n-major gather. Mapping is element-identical; numerics unchanged.
// ---------------------------------------------------------------------------
__global__ __launch_bounds__(256) void k_query(
    const float* __restrict__ tb_shot, const float* __restrict__ tb_query,
    const float* __restrict__ sum_ss,
    const _Float16* __restrict__ w2p_hi, const _Float16* __restrict__ w2p_lo,
    const float* __restrict__ b2,
    const float* __restrict__ F1, const float* __restrict__ fb1,
    const float* __restrict__ F2, const float* __restrict__ fb2,
    float* __restrict__ out)
{
    __shared__ __align__(16) _Float16 aHi[32 * 256];   // 16 KB
    __shared__ __align__(16) _Float16 aLo[32 * 256];   // 16 KB
    __shared__ __align__(16) float rel[2][DD];         //  2 KB
    __shared__ __align__(16) float red[256];           //  1 KB

    const int bq = blockIdx.x;           // b*32+q
    const int b  = bq >> 5;
    const int t  = threadIdx.x;
    const int tg = t >> 6;               // wave id / build row-group
    const int lane = t & 63;

    // ---- build phase: 24 layer-1 rows -> fp16 hi/lo in LDS (swizzled) ----
    // tg -> 6 rows, lane -> 4 consecutive cols.  (verified round 3)
    {
        const int c4 = lane * 4;                 // column (element) base
        const int w  = tg >> 1;                  // way
        const int side = tg & 1;                 // 0: sT+qB rows, 1: qT+sB rows
        const float4 qv = *(const float4*)&tb_query[(size_t)bq * 512 + (side ? 0 : 256) + c4];
        const float* gs = tb_shot + (size_t)b * 12 * 512 + (size_t)w * 6 * 512;
#pragma unroll
        for (int s = 0; s < 6; ++s) {
            const float4 sv = *(const float4*)&gs[s * 512 + (side ? 256 : 0) + c4];
            float v0 = sv.x + qv.x, v1 = sv.y + qv.y, v2 = sv.z + qv.z, v3 = sv.w + qv.w;
            v0 = v0 > 0.f ? v0 : 0.f;
            v1 = v1 > 0.f ? v1 : 0.f;
            v2 = v2 > 0.f ? v2 : 0.f;
            v3 = v3 > 0.f ? v3 : 0.f;
            half4 h, l;
            h.x = (_Float16)v0; l.x = (_Float16)(v0 - (float)h.x);
            h.y = (_Float16)v1; l.y = (_Float16)(v1 - (float)h.y);
            h.z = (_Float16)v2; l.z = (_Float16)(v2 - (float)h.z);
            h.w = (_Float16)v3; l.w = (_Float16)(v3 - (float)h.w);
            const int ar = w * 16 + side * 6 + s;                 // A row
            const int off = ar * 512 + ((lane * 8) ^ ((ar & 7) << 4));
            *(half4*)((char*)aHi + off) = h;
            *(half4*)((char*)aLo + off) = l;
        }
        // zero the pad rows 12..15 and 28..31 (hi and lo)
        half4 z; z.x = (_Float16)0.f; z.y = (_Float16)0.f; z.z = (_Float16)0.f; z.w = (_Float16)0.f;
        const int pr0 = 12 + tg, pr1 = 28 + tg;
        const int o0 = pr0 * 512 + ((lane * 8) ^ ((pr0 & 7) << 4));
        const int o1 = pr1 * 512 + ((lane * 8) ^ ((pr1 & 7) << 4));
        *(half4*)((char*)aHi + o0) = z;  *(half4*)((char*)aLo + o0) = z;
        *(half4*)((char*)aHi + o1) = z;  *(half4*)((char*)aLo + o1) = z;
    }
    __syncthreads();

    // ---- MFMA phase ----
    const int wv = tg;
    const int r  = lane & 15;            // A row-in-tile / B col-in-tile / D col
    const int gq = lane >> 4;            // k-group
    const int swz = (r & 7) << 4;
    f32x4 acc[2][4];
#pragma unroll
    for (int i = 0; i < 2; ++i)
#pragma unroll
        for (int j = 0; j < 4; ++j)
#pragma unroll
            for (int e = 0; e < 4; ++e) acc[i][j][e] = 0.f;

    const int aoff0 = r * 512;           // way-0 row byte base
    const int aoff1 = (16 + r) * 512;    // way-1
#pragma unroll
    for (int ks = 0; ks < 8; ++ks) {
        // B fragments: contiguous packed loads (the only change vs round 3)
        half8 bH[4], bL[4];
#pragma unroll
        for (int nt = 0; nt < 4; ++nt) {
            const size_t boff = ((size_t)(ks * 16 + wv * 4 + nt) * 64 + lane) * 8;
            bH[nt] = *(const half8*)&w2p_hi[boff];
            bL[nt] = *(const half8*)&w2p_lo[boff];
        }
        const int kb = (ks * 64 + gq * 16) ^ swz;          // swizzled k-byte
        const half8 aH0 = *(const half8*)((const char*)aHi + aoff0 + kb);
        const half8 aL0 = *(const half8*)((const char*)aLo + aoff0 + kb);
        const half8 aH1 = *(const half8*)((const char*)aHi + aoff1 + kb);
        const half8 aL1 = *(const half8*)((const char*)aLo + aoff1 + kb);
#pragma unroll
        for (int nt = 0; nt < 4; ++nt) {
            acc[0][nt] = __builtin_amdgcn_mfma_f32_16x16x32_f16(aH0, bH[nt], acc[0][nt], 0, 0, 0);
            acc[0][nt] = __builtin_amdgcn_mfma_f32_16x16x32_f16(aL0, bH[nt], acc[0][nt], 0, 0, 0);
            acc[0][nt] = __builtin_amdgcn_mfma_f32_16x16x32_f16(aH0, bL[nt], acc[0][nt], 0, 0, 0);
            acc[1][nt] = __builtin_amdgcn_mfma_f32_16x16x32_f16(aH1, bH[nt], acc[1][nt], 0, 0, 0);
            acc[1][nt] = __builtin_amdgcn_mfma_f32_16x16x32_f16(aL1, bH[nt], acc[1][nt], 0, 0, 0);
            acc[1][nt] = __builtin_amdgcn_mfma_f32_16x16x32_f16(aH1, bL[nt], acc[1][nt], 0, 0, 0);
        }
    }

    // ---- epilogue: rel[w][n] = ss + sum_rows ReLU(acc + b2) ----
    // D layout: col = lane&15, row = (lane>>4)*4 + j. Rows 12..15 (gq==3) are pad.
#pragma unroll
    for (int nt = 0; nt < 4; ++nt) {
        const int n = (wv * 4 + nt) * 16 + r;
        const float b2n = b2[n];
#pragma unroll
        for (int w = 0; w < 2; ++w) {
            float p = 0.f;
            if (gq != 3) {
#pragma unroll
                for (int j = 0; j < 4; ++j) {
                    const float h = acc[w][nt][j] + b2n;
                    p += h > 0.f ? h : 0.f;
                }
            }
            p += __shfl_xor(p, 16);
            p += __shfl_xor(p, 32);
            if (lane < 16) rel[w][n] = p + sum_ss[(size_t)b * 512 + w * 256 + n];
        }
    }
    __syncthreads();

    // ---- f-MLP: f = ReLU(rel @ F1 + fb1); logit = f @ F2 + fb2 ----
    {
        const int wf = t >> 7;
        const int n0 = (t & 127) * 2;
        float f0 = 0.f, f1 = 0.f;
        for (int k4 = 0; k4 < 64; ++k4) {
            const int kb = k4 * 4;
            const float4 rv = *(const float4*)&rel[wf][kb];
            const float2 g0 = *(const float2*)&F1[(kb+0)*256 + n0];
            const float2 g1 = *(const float2*)&F1[(kb+1)*256 + n0];
            const float2 g2 = *(const float2*)&F1[(kb+2)*256 + n0];
            const float2 g3 = *(const float2*)&F1[(kb+3)*256 + n0];
            f0 += rv.x*g0.x + rv.y*g1.x + rv.z*g2.x + rv.w*g3.x;
            f1 += rv.x*g0.y + rv.y*g1.y + rv.z*g2.y + rv.w*g3.y;
        }
        f0 += fb1[n0];     f0 = f0 > 0.f ? f0 : 0.f;
        f1 += fb1[n0 + 1]; f1 = f1 > 0.f ? f1 : 0.f;
        red[t] = f0 * F2[n0] + f1 * F2[n0 + 1];
    }
    __syncthreads();
#pragma unroll
    for (int off = 64; off >= 1; off >>= 1) {
        if ((t & 127) < off) red[t] += red[t + off];
        __syncthreads();
    }
    if (t == 0)   out[(size_t)bq * 2 + 0] = red[0]   + fb2[0];
    if (t == 128) out[(size_t)bq * 2 + 1] = red[128] + fb2[0];
}

// ---------------------------------------------------------------------------
extern "C" void kernel_launch(void* const* d_in, const int* in_sizes, int n_in,
                              void* d_out, int out_size, void* d_ws, size_t ws_size,
                              hipStream_t stream)
{
    const float* x_shot  = (const float*)d_in[0];
    const float* x_query = (const float*)d_in[1];
    const float* W1  = (const float*)d_in[2];
    const float* b1  = (const float*)d_in[3];
    const float* W2  = (const float*)d_in[4];
    const float* b2  = (const float*)d_in[5];
    const float* F1  = (const float*)d_in[6];
    const float* fb1 = (const float*)d_in[7];
    const float* F2  = (const float*)d_in[8];
    const float* fb2 = (const float*)d_in[9];
    float* out = (float*)d_out;
    float* ws  = (float*)d_ws;

    float* tb_shot  = ws + TB_SHOT_OFF;
    float* tb_query = ws + TB_QUERY_OFF;
    float* sum_ss   = ws + SUM_SS_OFF;
    _Float16* w2p_hi = (_Float16*)(ws + W2P_OFF);
    _Float16* w2p_lo = w2p_hi + 128 * 512;

    hipLaunchKernelGGL(k_prep, dim3(32), dim3(256), 0, stream, W2, w2p_hi, w2p_lo);
    hipLaunchKernelGGL(k_embed, dim3(352), dim3(256), 0, stream,
                       x_shot, x_query, W1, b1, tb_shot, tb_query);
    hipLaunchKernelGGL(k_shotpairs, dim3(256), dim3(256), 0, stream,
                       tb_shot, W2, b2, sum_ss);
    hipLaunchKernelGGL(k_query, dim3(4096), dim3(256), 0, stream,
                       tb_shot, tb_query, sum_ss, w2p_hi, w2p_lo, b2,
                       F1, fb1, F2, fb2, out);
}